// Round 4
// baseline (262.098 us; speedup 1.0000x reference)
//
#include <hip/hip_runtime.h>
#include <cstdint>
#include <cstddef>

#define NROWS 8192
#define DIM   25
#define CIN   128
#define COUT  128
#define MAXT  160

// ---------------- compile-time path tables (mirrors reference _build_paths) --
struct Tables {
  int   w_idx[MAXT];     // per original entry t: weight row
  float coef[MAXT];      // per original entry t: signed coefficient
  int   o_start[DIM + 1];
  int   e_in[MAXT];      // bucketed-by-o: input DIM row
  int   e_t[MAXT];       // bucketed-by-o: original entry index (row of Bt)
  int   T;
};

constexpr Tables build_tables() {
  Tables tb{};
  int off[5] = {0, 1, 4, 9, 16};
  const float pn = 0.44721359549995793f;  // 1/sqrt(5)
  int in_idx[MAXT] = {}, out_idx[MAXT] = {}, widx[MAXT] = {};
  float cf[MAXT] = {};
  int T = 0, w = 0;
  for (int lo = 0; lo < 5; ++lo) {
    for (int li = 0; li < 5; ++li) {
      int oi = off[li], oo = off[lo];
      in_idx[T] = oi + li; out_idx[T] = oo + lo; widx[T] = w; cf[T] = pn; ++T; ++w;
      int mm = li < lo ? li : lo;
      for (int m = 1; m <= mm; ++m) {
        int ip = oi + li + m, im = oi + li - m;
        int op = oo + lo + m, om = oo + lo - m;
        int wre = w, wim = w + 1; w += 2;
        in_idx[T] = ip; out_idx[T] = op; widx[T] = wre; cf[T] = pn;  ++T;
        in_idx[T] = im; out_idx[T] = om; widx[T] = wre; cf[T] = pn;  ++T;
        in_idx[T] = ip; out_idx[T] = om; widx[T] = wim; cf[T] = pn;  ++T;
        in_idx[T] = im; out_idx[T] = op; widx[T] = wim; cf[T] = -pn; ++T;
      }
    }
  }
  tb.T = T;  // 145
  for (int t = 0; t < T; ++t) { tb.w_idx[t] = widx[t]; tb.coef[t] = cf[t]; }
  int pos = 0;
  for (int o = 0; o < DIM; ++o) {
    tb.o_start[o] = pos;
    for (int t = 0; t < T; ++t)
      if (out_idx[t] == o) { tb.e_in[pos] = in_idx[t]; tb.e_t[pos] = t; ++pos; }
  }
  tb.o_start[DIM] = pos;
  return tb;
}

__constant__ Tables TAB = build_tables();

// ---------------- helpers ----------------------------------------------------
__device__ __forceinline__ uint16_t f2bf(float f) {
  uint32_t u = __float_as_uint(f);
  uint32_t r = (u + 0x7FFFu + ((u >> 16) & 1u)) >> 16;
  return (uint16_t)r;
}

__device__ __forceinline__ void load_lds16(const void* g, void* l) {
  __builtin_amdgcn_global_load_lds(
      (const __attribute__((address_space(1))) uint32_t*)g,
      (__attribute__((address_space(3))) uint32_t*)l, 16, 0, 0);
}

typedef __bf16 v8bf __attribute__((ext_vector_type(8)));
typedef float  v4f  __attribute__((ext_vector_type(4)));

// pack two float4 into 8 bf16 (compiler emits v_cvt_pk_bf16_f32 — RNE)
__device__ __forceinline__ v8bf cvt8(float4 p, float4 q) {
  v8bf v;
  v[0] = (__bf16)p.x; v[1] = (__bf16)p.y; v[2] = (__bf16)p.z; v[3] = (__bf16)p.w;
  v[4] = (__bf16)q.x; v[5] = (__bf16)q.y; v[6] = (__bf16)q.z; v[7] = (__bf16)q.w;
  return v;
}

// ---------------- kernel 1: weight prep only ---------------------------------
// LDS-tiled transpose+scale of weights: Bt[t][d][c] = coef[t]*W[w_idx[t]][c][d]
// 4 blocks per t (32 d each). ~7 MB of traffic -> a few microseconds.
#define NWB  (145 * 4)

__global__ void prep_kernel(const float* __restrict__ W, uint16_t* __restrict__ Bt) {
  __shared__ float tile[128][33];
  int b  = blockIdx.x;
  int t  = b >> 2;
  int d0 = (b & 3) << 5;                  // 32 d-values per block
  int w  = TAB.w_idx[t];
  float cf = TAB.coef[t];
  const float* Wp = W + (size_t)w * CIN * COUT;
  uint16_t* Bp = Bt + (size_t)t * CIN * COUT;
  int tid = threadIdx.x;
  // read: coalesced 32-float (128B) rows of W[c][d0..d0+31]
  {
    int dcol = tid & 31, cbase = tid >> 5;     // 8 c-rows per pass
    #pragma unroll
    for (int r = 0; r < 16; ++r) {
      int c = (r << 3) + cbase;
      tile[c][dcol] = cf * Wp[(size_t)c * COUT + d0 + dcol];
    }
  }
  __syncthreads();
  // write: coalesced bf16 rows of Bt[t][d][c] (c contiguous)
  {
    int c = tid & 127, dbase = tid >> 7;       // 2 d-rows per pass
    #pragma unroll
    for (int r = 0; r < 16; ++r) {
      int dd = (r << 1) + dbase;
      Bp[(size_t)(d0 + dd) * CIN + c] = f2bf(tile[c][dd]);
    }
  }
}

// ---------------- kernel 2: fused cast + grouped GEMM ------------------------
// Per block: Out[n0..n0+127][o][0..127] = sum_e X[n][IN[e]][:] . Bt[e_t][:][:]
// Round-4: round-3's fusion (read fp32 X directly; no 157MB cast pass) with
// the register budget FIXED. Round-3 failed because __launch_bounds__(512,4)
// capped the unified VGPR+AGPR file at 128: acc=64 AGPR left 64 VGPR and the
// 32-VGPR a_st staging spilled to scratch (WRITE_SIZE 102->144MB). Here:
//   - BM=128, 256 threads, 4 waves (round-0's proven geometry): acc 64 AGPR +
//     a_st 32 VGPR + frags fit at ~3 waves/SIMD with NO forced cap.
//   - LDS 48 KB (As 16K single + Bs 2x16K dbuf) -> 3 blocks/CU: three
//     independent blocks provide the latency hiding r1/r3 lost.
//   - T14 split: A global float4 loads + B global_load_lds issued BEFORE the
//     MFMA phase; the barrier's vmcnt(0) drain lands a full compute phase
//     after issue. cvt (v_cvt_pk_bf16_f32) + swizzled ds_write after barrier.
// Grid: XCD-aware, o sweeps fastest so each X slab is L2-reused 25x.
__global__ __launch_bounds__(256) void so2_gemm(
    const float* __restrict__ X,       // [NROWS][DIM][CIN] fp32
    const uint16_t* __restrict__ Bt,   // [T][COUT][CIN]    bf16 bits
    float* __restrict__ Out) {         // [NROWS][DIM][COUT]
  __shared__ __align__(16) uint16_t As[128 * 64];      // 16 KB, single buffer
  __shared__ __align__(16) uint16_t Bs[2][128 * 64];   // 2 x 16 KB

  // XCD-aware decode: lb -> (o, n-tile)
  const int lb   = blockIdx.x;            // 0..1599
  const int xcd  = lb & 7;
  const int slot = lb >> 3;               // 0..199
  const int o    = slot % 25;             // o sweeps fastest within an XCD
  const int nt   = xcd + ((slot / 25) << 3);   // 0..63
  const int n0   = nt << 7;               // 128 rows per tile

  const int e0 = TAB.o_start[o];
  const int nE = TAB.o_start[o + 1] - e0;

  const int tid  = threadIdx.x;
  const int w    = tid >> 6;              // 0..3
  const int l    = tid & 63;

  // B staging (global_load_lds, round-0-proven geometry):
  // per issue j, rows m = j*32 + srow; LDS slot l%8; src chunk slt^(m%8)
  const int srow = (w << 3) + (l >> 3);          // 0..31
  const int slt  = l & 7;
  const int ssrc = ((slt ^ (l >> 3)) << 3);      // pre-swizzled global chunk

  // A staging (reg + cvt + ds_write): thread covers rows arow + j*32 (j=0..3),
  // bf16 chunk achk (8 channels = 16B LDS = 32B fp32 source)
  const int arow = tid >> 3;                     // 0..31
  const int achk = tid & 7;
  const int aslt = achk ^ (arow & 7);            // swizzled chunk slot (32%8==0)
  const float* gAbase = X + (size_t)(n0 + arow) * DIM * CIN + (achk << 3);
  uint16_t* lAbase = &As[arow * 64 + aslt * 8];

  // compute geometry: wave grid 2 (rows) x 2 (cols), 64x64 per wave
  const int lr   = l & 15;
  const int quad = l >> 4;
  const int wr   = (w & 1) << 6;
  const int wc   = (w >> 1) << 6;

  v4f acc[4][4];
  #pragma unroll
  for (int i = 0; i < 4; ++i)
    #pragma unroll
    for (int j = 0; j < 4; ++j)
      acc[i][j] = v4f{0.f, 0.f, 0.f, 0.f};

  const int nIter = nE << 1;

  // ---- prologue: stage K-step 0 (A via regs, B into Bs[0]) ----
  {
    const int irow = TAB.e_in[e0];
    const int trow = TAB.e_t[e0];
    const uint16_t* gB = Bt + ((size_t)trow * COUT + srow) * CIN + ssrc;
    #pragma unroll
    for (int j = 0; j < 4; ++j)
      load_lds16(gB + (size_t)(j << 5) * CIN,
                 &Bs[0][((j << 5) + srow) * 64 + slt * 8]);

    float4 a_st[8];
    const float* gA = gAbase + (size_t)irow * CIN;
    #pragma unroll
    for (int j = 0; j < 4; ++j) {
      const float4* p = (const float4*)(gA + (size_t)(j << 5) * (DIM * CIN));
      a_st[2 * j]     = p[0];
      a_st[2 * j + 1] = p[1];
    }
    #pragma unroll
    for (int j = 0; j < 4; ++j)
      *(v8bf*)(lAbase + (j << 5) * 64) = cvt8(a_st[2 * j], a_st[2 * j + 1]);
  }
  __syncthreads();                         // A(0), B(0) visible

  for (int ki = 0; ki < nIter; ++ki) {
    const int cur  = ki & 1;
    const bool more = (ki + 1 < nIter);

    // issue next K-step's loads BEFORE compute (latency hides under MFMAs)
    float4 a_st[8];
    if (more) {
      const int kn   = ki + 1;
      const int e    = e0 + (kn >> 1);
      const int kk   = (kn & 1) << 6;
      const int irow = TAB.e_in[e];
      const int trow = TAB.e_t[e];
      const uint16_t* gB = Bt + ((size_t)trow * COUT + srow) * CIN + kk + ssrc;
      #pragma unroll
      for (int j = 0; j < 4; ++j)
        load_lds16(gB + (size_t)(j << 5) * CIN,
                   &Bs[cur ^ 1][((j << 5) + srow) * 64 + slt * 8]);
      const float* gA = gAbase + (size_t)irow * CIN + kk;
      #pragma unroll
      for (int j = 0; j < 4; ++j) {
        const float4* p = (const float4*)(gA + (size_t)(j << 5) * (DIM * CIN));
        a_st[2 * j]     = p[0];
        a_st[2 * j + 1] = p[1];
      }
    }

    // compute current K-step
    #pragma unroll
    for (int kk2 = 0; kk2 < 2; ++kk2) {
      const int s = (((kk2 << 2) + quad) ^ (lr & 7)) << 3;
      v8bf a[4], b[4];
      #pragma unroll
      for (int i = 0; i < 4; ++i) {
        a[i] = *(const v8bf*)(&As[(wr + (i << 4) + lr) * 64 + s]);
        b[i] = *(const v8bf*)(&Bs[cur][(wc + (i << 4) + lr) * 64 + s]);
      }
      #pragma unroll
      for (int i = 0; i < 4; ++i)
        #pragma unroll
        for (int j = 0; j < 4; ++j)
          acc[i][j] = __builtin_amdgcn_mfma_f32_16x16x32_bf16(a[i], b[j],
                                                              acc[i][j], 0, 0, 0);
    }

    if (more) {
      __syncthreads();   // all reads of As/Bs[cur] done; vmcnt(0) drained —
                         // a_st ready & B(k+1) landed, both issued a phase ago
      #pragma unroll
      for (int j = 0; j < 4; ++j)
        *(v8bf*)(lAbase + (j << 5) * 64) = cvt8(a_st[2 * j], a_st[2 * j + 1]);
      __syncthreads();   // lgkm drain: As(k+1) visible
    }
  }

  // epilogue: C/D layout col = lane&15 (d), row = quad*4 + r (n)
  #pragma unroll
  for (int i = 0; i < 4; ++i) {
    #pragma unroll
    for (int r = 0; r < 4; ++r) {
      const int n = n0 + wr + (i << 4) + (quad << 2) + r;
      float* op = Out + ((size_t)n * DIM + o) * COUT + wc + lr;
      #pragma unroll
      for (int j = 0; j < 4; ++j)
        op[j << 4] = acc[i][j][r];
    }
  }
}

// ---------------- launcher ---------------------------------------------------
extern "C" void kernel_launch(void* const* d_in, const int* in_sizes, int n_in,
                              void* d_out, int out_size, void* d_ws, size_t ws_size,
                              hipStream_t stream) {
  const float* X = (const float*)d_in[0];   // [8192][25][128]
  const float* W = (const float*)d_in[1];   // [85][128][128]
  float* Out = (float*)d_out;

  uint16_t* Bt = (uint16_t*)d_ws;           // 4.75 MB (only workspace use)

  // 1) tiny weight transpose/scale (fp32 -> bf16)
  prep_kernel<<<NWB, 256, 0, stream>>>(W, Bt);
  // 2) fused cast+GEMM, XCD-swizzled 1-D grid, 128-row tiles
  so2_gemm<<<DIM * (NROWS / 128), 256, 0, stream>>>(X, Bt, Out);
}

// Round 5
// 252.484 us; speedup vs baseline: 1.0381x; 1.0381x over previous
//
#include <hip/hip_runtime.h>
#include <cstdint>
#include <cstddef>

#define NROWS 8192
#define DIM   25
#define CIN   128
#define COUT  128
#define MAXT  160

// ---------------- compile-time path tables (mirrors reference _build_paths) --
struct Tables {
  int   w_idx[MAXT];     // per original entry t: weight row
  float coef[MAXT];      // per original entry t: signed coefficient
  int   o_start[DIM + 1];
  int   e_in[MAXT];      // bucketed-by-o: input DIM row
  int   e_t[MAXT];       // bucketed-by-o: original entry index (row of Bt)
  int   T;
};

constexpr Tables build_tables() {
  Tables tb{};
  int off[5] = {0, 1, 4, 9, 16};
  const float pn = 0.44721359549995793f;  // 1/sqrt(5)
  int in_idx[MAXT] = {}, out_idx[MAXT] = {}, widx[MAXT] = {};
  float cf[MAXT] = {};
  int T = 0, w = 0;
  for (int lo = 0; lo < 5; ++lo) {
    for (int li = 0; li < 5; ++li) {
      int oi = off[li], oo = off[lo];
      in_idx[T] = oi + li; out_idx[T] = oo + lo; widx[T] = w; cf[T] = pn; ++T; ++w;
      int mm = li < lo ? li : lo;
      for (int m = 1; m <= mm; ++m) {
        int ip = oi + li + m, im = oi + li - m;
        int op = oo + lo + m, om = oo + lo - m;
        int wre = w, wim = w + 1; w += 2;
        in_idx[T] = ip; out_idx[T] = op; widx[T] = wre; cf[T] = pn;  ++T;
        in_idx[T] = im; out_idx[T] = om; widx[T] = wre; cf[T] = pn;  ++T;
        in_idx[T] = ip; out_idx[T] = om; widx[T] = wim; cf[T] = pn;  ++T;
        in_idx[T] = im; out_idx[T] = op; widx[T] = wim; cf[T] = -pn; ++T;
      }
    }
  }
  tb.T = T;  // 145
  for (int t = 0; t < T; ++t) { tb.w_idx[t] = widx[t]; tb.coef[t] = cf[t]; }
  int pos = 0;
  for (int o = 0; o < DIM; ++o) {
    tb.o_start[o] = pos;
    for (int t = 0; t < T; ++t)
      if (out_idx[t] == o) { tb.e_in[pos] = in_idx[t]; tb.e_t[pos] = t; ++pos; }
  }
  tb.o_start[DIM] = pos;
  return tb;
}

__constant__ Tables TAB = build_tables();

// ---------------- helpers ----------------------------------------------------
__device__ __forceinline__ uint16_t f2bf(float f) {
  uint32_t u = __float_as_uint(f);
  uint32_t r = (u + 0x7FFFu + ((u >> 16) & 1u)) >> 16;
  return (uint16_t)r;
}

__device__ __forceinline__ void load_lds16(const void* g, void* l) {
  __builtin_amdgcn_global_load_lds(
      (const __attribute__((address_space(1))) uint32_t*)g,
      (__attribute__((address_space(3))) uint32_t*)l, 16, 0, 0);
}

typedef __bf16 v8bf __attribute__((ext_vector_type(8)));
typedef float  v4f  __attribute__((ext_vector_type(4)));

// ---------------- kernel 1: fused prep ---------------------------------------
// blocks [0, NCVT): fp32 -> bf16 cast of input (2x float4 per thread)
// blocks [NCVT, NCVT+580): LDS-tiled transpose of weights:
//   Bt[t][d][c] = coef[t] * W[w_idx[t]][c][d], 4 blocks per t (32 d each)
#define NCVT (NROWS * DIM * CIN / 4 / 512)   // 12800 blocks, 512 float4 each
#define NWB  (145 * 4)

__global__ void prep_kernel(const float* __restrict__ X, uint16_t* __restrict__ Y,
                            const float* __restrict__ W, uint16_t* __restrict__ Bt) {
  if (blockIdx.x < NCVT) {
    int i0 = blockIdx.x * 512 + threadIdx.x;
    #pragma unroll
    for (int r = 0; r < 2; ++r) {
      int i = i0 + (r << 8);
      float4 v = ((const float4*)X)[i];
      ushort4 o;
      o.x = f2bf(v.x); o.y = f2bf(v.y); o.z = f2bf(v.z); o.w = f2bf(v.w);
      ((ushort4*)Y)[i] = o;
    }
  } else {
    __shared__ float tile[128][33];
    int b  = blockIdx.x - NCVT;
    int t  = b >> 2;
    int d0 = (b & 3) << 5;                  // 32 d-values per block
    int w  = TAB.w_idx[t];
    float cf = TAB.coef[t];
    const float* Wp = W + (size_t)w * CIN * COUT;
    uint16_t* Bp = Bt + (size_t)t * CIN * COUT;
    int tid = threadIdx.x;
    // read: coalesced 32-float (128B) rows of W[c][d0..d0+31]
    {
      int dcol = tid & 31, cbase = tid >> 5;     // 8 c-rows per pass
      #pragma unroll
      for (int r = 0; r < 16; ++r) {
        int c = (r << 3) + cbase;
        tile[c][dcol] = cf * Wp[(size_t)c * COUT + d0 + dcol];
      }
    }
    __syncthreads();
    // write: coalesced bf16 rows of Bt[t][d][c] (c contiguous)
    {
      int c = tid & 127, dbase = tid >> 7;       // 2 d-rows per pass
      #pragma unroll
      for (int r = 0; r < 16; ++r) {
        int dd = (r << 1) + dbase;
        Bp[(size_t)(d0 + dd) * CIN + c] = f2bf(tile[c][dd]);
      }
    }
  }
}

// ---------------- kernel 2: main GEMM ----------------------------------------
// Per block: Out[n0..n0+255][o][0..127] = sum_e Xb[n][IN[e]][:] . Bt[e_t][:][:]
// Round-5 = round-2 (best measured) + "minimum 2-phase" pipeline, which is
// now FREE: at BM=256/8 waves the unified regfile (acc 64 AGPR + ~88 VGPR ~
// 152/wave -> 3 waves/SIMD) already caps residency at 1 block/CU, so LDS
// 48->96 KB (full A+B double-buffer) costs zero occupancy. Per K-step:
//   stage(k+1 -> buf^1)  [6 global_load_lds issued FIRST]
//   compute(buf)         [ds_read + 32 MFMA per wave]
//   __syncthreads()      [vmcnt(0) drain lands a full compute phase after
//                         issue -> L2 latency hidden; 1 barrier/K-step not 2]
// Race audit: buf^1 was last read in iter k-1 and freed by that iter's
// barrier; compute(k) reads the buffer staged+barrier-confirmed in iter k-1.
// Staging uses the proven XOR chunk swizzle (0 conflicts measured).
// Grid: XCD-aware, o sweeps fastest so each n-slab is L2-reused 25x.
__global__ __launch_bounds__(512) void so2_gemm(
    const uint16_t* __restrict__ Xb,   // [NROWS][DIM][CIN] bf16 bits
    const uint16_t* __restrict__ Bt,   // [T][COUT][CIN]    bf16 bits
    float* __restrict__ Out) {         // [NROWS][DIM][COUT]
  __shared__ __align__(16) uint16_t As[2][256 * 64];   // 2 x 32 KB
  __shared__ __align__(16) uint16_t Bs[2][128 * 64];   // 2 x 16 KB

  // XCD-aware decode: lb -> (o, n-tile)
  const int lb   = blockIdx.x;            // 0..799
  const int xcd  = lb & 7;
  const int slot = lb >> 3;               // 0..99
  const int o    = slot % 25;             // o sweeps fastest within an XCD
  const int nt   = xcd + ((slot / 25) << 3);   // 0..31
  const int n0   = nt << 8;               // 256 rows per tile

  const int e0 = TAB.o_start[o];
  const int nE = TAB.o_start[o + 1] - e0;

  const int tid  = threadIdx.x;
  const int w    = tid >> 6;              // 0..7
  const int l    = tid & 63;

  // staging geometry: per issue j, rows m = j*64 + srow, LDS slot = l%8,
  // global source chunk = slot ^ (m%8)   (m%8 == l>>3 since w*8 ≡ 0 mod 8)
  const int srow = (w << 3) + (l >> 3);          // 0..63
  const int slt  = l & 7;
  const int ssrc = ((slt ^ (l >> 3)) << 3);      // element offset 0..56

  // compute geometry: wave grid 4 (rows) x 2 (cols), 64x64 per wave
  const int lr   = l & 15;
  const int quad = l >> 4;
  const int wr   = (w & 3) << 6;                 // 0,64,128,192
  const int wc   = (w >> 2) << 6;                // 0,64

  // stage K-step ki (entry e0+ki/2, channel half ki%2) into buffer buf.
  auto stage = [&](int ki, int buf) {
    const int e    = e0 + (ki >> 1);
    const int kk   = (ki & 1) << 6;            // channel half: 0 or 64
    const int irow = TAB.e_in[e];
    const int trow = TAB.e_t[e];
    const uint16_t* gA = Xb + ((size_t)(n0 + srow) * DIM + irow) * CIN + kk + ssrc;
    const uint16_t* gB = Bt + ((size_t)trow * COUT + srow) * CIN + kk + ssrc;
    #pragma unroll
    for (int j = 0; j < 4; ++j) {
      const int m = (j << 6) + srow;
      load_lds16(gA + (size_t)(j << 6) * (DIM * CIN), &As[buf][m * 64 + slt * 8]);
    }
    #pragma unroll
    for (int j = 0; j < 2; ++j) {
      const int m = (j << 6) + srow;
      load_lds16(gB + (size_t)(j << 6) * CIN, &Bs[buf][m * 64 + slt * 8]);
    }
  };

  v4f acc[4][4];
  #pragma unroll
  for (int i = 0; i < 4; ++i)
    #pragma unroll
    for (int j = 0; j < 4; ++j)
      acc[i][j] = v4f{0.f, 0.f, 0.f, 0.f};

  const int nIter = nE << 1;

  // prologue: stage K-step 0 into buffer 0
  stage(0, 0);
  __syncthreads();                              // buf0 staged (vmcnt drained)

  for (int ki = 0; ki < nIter; ++ki) {
    const int cur  = ki & 1;
    const bool more = (ki + 1 < nIter);

    // issue next K-step's loads BEFORE compute: their vmcnt(0) drain at the
    // end-of-iteration barrier lands a full compute phase after issue.
    if (more) stage(ki + 1, cur ^ 1);

    #pragma unroll
    for (int kk2 = 0; kk2 < 2; ++kk2) {
      const int s = (((kk2 << 2) + quad) ^ (lr & 7)) << 3;
      v8bf a[4], b[4];
      #pragma unroll
      for (int i = 0; i < 4; ++i) {
        a[i] = *(const v8bf*)(&As[cur][(wr + (i << 4) + lr) * 64 + s]);
        b[i] = *(const v8bf*)(&Bs[cur][(wc + (i << 4) + lr) * 64 + s]);
      }
      #pragma unroll
      for (int i = 0; i < 4; ++i)
        #pragma unroll
        for (int j = 0; j < 4; ++j)
          acc[i][j] = __builtin_amdgcn_mfma_f32_16x16x32_bf16(a[i], b[j],
                                                              acc[i][j], 0, 0, 0);
    }

    // one barrier per K-step: next buffer's loads landed (issued a phase ago)
    // AND buf[cur] is confirmed free for re-staging next iteration.
    if (more) __syncthreads();
  }

  // epilogue: C/D layout col = lane&15 (d), row = quad*4 + r (n)
  #pragma unroll
  for (int i = 0; i < 4; ++i) {
    #pragma unroll
    for (int r = 0; r < 4; ++r) {
      const int n = n0 + wr + (i << 4) + (quad << 2) + r;
      float* op = Out + ((size_t)n * DIM + o) * COUT + wc + lr;
      #pragma unroll
      for (int j = 0; j < 4; ++j)
        op[j << 4] = acc[i][j][r];
    }
  }
}

// ---------------- launcher ---------------------------------------------------
extern "C" void kernel_launch(void* const* d_in, const int* in_sizes, int n_in,
                              void* d_out, int out_size, void* d_ws, size_t ws_size,
                              hipStream_t stream) {
  const float* X = (const float*)d_in[0];   // [8192][25][128]
  const float* W = (const float*)d_in[1];   // [85][128][128]
  float* Out = (float*)d_out;

  uint16_t* Xb = (uint16_t*)d_ws;                                   // 52.4 MB
  uint16_t* Bt = (uint16_t*)((char*)d_ws + (size_t)NROWS * DIM * CIN * 2);  // 4.75 MB

  // 1) fused prep: input fp32->bf16 cast + LDS-tiled weight transpose
  prep_kernel<<<NCVT + NWB, 256, 0, stream>>>(X, Xb, W, Bt);
  // 2) grouped GEMM, XCD-swizzled 1-D grid, 256-row tiles, 2-phase pipeline
  so2_gemm<<<DIM * (NROWS / 256), 512, 0, stream>>>(Xb, Bt, Out);
}

// Round 6
// 232.522 us; speedup vs baseline: 1.1272x; 1.0858x over previous
//
#include <hip/hip_runtime.h>
#include <cstdint>
#include <cstddef>

#define NROWS 8192
#define DIM   25
#define CIN   128
#define COUT  128
#define MAXT  160

// ---------------- compile-time path tables (mirrors reference _build_paths) --
struct Tables {
  int   w_idx[MAXT];     // per original entry t: weight row
  float coef[MAXT];      // per original entry t: signed coefficient
  int   o_start[DIM + 1];
  int   e_in[MAXT];      // bucketed-by-o: input DIM row
  int   e_t[MAXT];       // bucketed-by-o: original entry index (row of Bt)
  int   o_lpt[DIM];      // o indices sorted by descending entry count (LPT)
  int   T;
};

constexpr Tables build_tables() {
  Tables tb{};
  int off[5] = {0, 1, 4, 9, 16};
  const float pn = 0.44721359549995793f;  // 1/sqrt(5)
  int in_idx[MAXT] = {}, out_idx[MAXT] = {}, widx[MAXT] = {};
  float cf[MAXT] = {};
  int T = 0, w = 0;
  for (int lo = 0; lo < 5; ++lo) {
    for (int li = 0; li < 5; ++li) {
      int oi = off[li], oo = off[lo];
      in_idx[T] = oi + li; out_idx[T] = oo + lo; widx[T] = w; cf[T] = pn; ++T; ++w;
      int mm = li < lo ? li : lo;
      for (int m = 1; m <= mm; ++m) {
        int ip = oi + li + m, im = oi + li - m;
        int op = oo + lo + m, om = oo + lo - m;
        int wre = w, wim = w + 1; w += 2;
        in_idx[T] = ip; out_idx[T] = op; widx[T] = wre; cf[T] = pn;  ++T;
        in_idx[T] = im; out_idx[T] = om; widx[T] = wre; cf[T] = pn;  ++T;
        in_idx[T] = ip; out_idx[T] = om; widx[T] = wim; cf[T] = pn;  ++T;
        in_idx[T] = im; out_idx[T] = op; widx[T] = wim; cf[T] = -pn; ++T;
      }
    }
  }
  tb.T = T;  // 145
  for (int t = 0; t < T; ++t) { tb.w_idx[t] = widx[t]; tb.coef[t] = cf[t]; }
  int pos = 0;
  for (int o = 0; o < DIM; ++o) {
    tb.o_start[o] = pos;
    for (int t = 0; t < T; ++t)
      if (out_idx[t] == o) { tb.e_in[pos] = in_idx[t]; tb.e_t[pos] = t; ++pos; }
  }
  tb.o_start[DIM] = pos;
  // LPT order: o sorted by descending nE (stable: ascending o on ties).
  // Heavy blocks (nIter = 2*nE up to 16) dispatch first within each n-tile
  // group, so the kernel drains on light (nIter=4) blocks -> shorter tail.
  for (int i = 0; i < DIM; ++i) tb.o_lpt[i] = i;
  for (int i = 0; i < DIM; ++i) {
    int best = i;
    for (int j = i + 1; j < DIM; ++j) {
      int nb = tb.o_start[tb.o_lpt[best] + 1] - tb.o_start[tb.o_lpt[best]];
      int nj = tb.o_start[tb.o_lpt[j] + 1] - tb.o_start[tb.o_lpt[j]];
      if (nj > nb) best = j;
    }
    int tmp = tb.o_lpt[i]; tb.o_lpt[i] = tb.o_lpt[best]; tb.o_lpt[best] = tmp;
  }
  return tb;
}

__constant__ Tables TAB = build_tables();

// ---------------- helpers ----------------------------------------------------
__device__ __forceinline__ uint16_t f2bf(float f) {
  uint32_t u = __float_as_uint(f);
  uint32_t r = (u + 0x7FFFu + ((u >> 16) & 1u)) >> 16;
  return (uint16_t)r;
}

__device__ __forceinline__ void load_lds16(const void* g, void* l) {
  __builtin_amdgcn_global_load_lds(
      (const __attribute__((address_space(1))) uint32_t*)g,
      (__attribute__((address_space(3))) uint32_t*)l, 16, 0, 0);
}

typedef __bf16 v8bf __attribute__((ext_vector_type(8)));
typedef float  v4f  __attribute__((ext_vector_type(4)));

// ---------------- kernel 1: fused prep ---------------------------------------
// blocks [0, NCVT): fp32 -> bf16 cast of input (2x float4 per thread)
// blocks [NCVT, NCVT+580): LDS-tiled transpose of weights:
//   Bt[t][d][c] = coef[t] * W[w_idx[t]][c][d], 4 blocks per t (32 d each)
#define NCVT (NROWS * DIM * CIN / 4 / 512)   // 12800 blocks, 512 float4 each
#define NWB  (145 * 4)

__global__ void prep_kernel(const float* __restrict__ X, uint16_t* __restrict__ Y,
                            const float* __restrict__ W, uint16_t* __restrict__ Bt) {
  if (blockIdx.x < NCVT) {
    int i0 = blockIdx.x * 512 + threadIdx.x;
    #pragma unroll
    for (int r = 0; r < 2; ++r) {
      int i = i0 + (r << 8);
      float4 v = ((const float4*)X)[i];
      ushort4 o;
      o.x = f2bf(v.x); o.y = f2bf(v.y); o.z = f2bf(v.z); o.w = f2bf(v.w);
      ((ushort4*)Y)[i] = o;
    }
  } else {
    __shared__ float tile[128][33];
    int b  = blockIdx.x - NCVT;
    int t  = b >> 2;
    int d0 = (b & 3) << 5;                  // 32 d-values per block
    int w  = TAB.w_idx[t];
    float cf = TAB.coef[t];
    const float* Wp = W + (size_t)w * CIN * COUT;
    uint16_t* Bp = Bt + (size_t)t * CIN * COUT;
    int tid = threadIdx.x;
    // read: coalesced 32-float (128B) rows of W[c][d0..d0+31]
    {
      int dcol = tid & 31, cbase = tid >> 5;     // 8 c-rows per pass
      #pragma unroll
      for (int r = 0; r < 16; ++r) {
        int c = (r << 3) + cbase;
        tile[c][dcol] = cf * Wp[(size_t)c * COUT + d0 + dcol];
      }
    }
    __syncthreads();
    // write: coalesced bf16 rows of Bt[t][d][c] (c contiguous)
    {
      int c = tid & 127, dbase = tid >> 7;       // 2 d-rows per pass
      #pragma unroll
      for (int r = 0; r < 16; ++r) {
        int dd = (r << 1) + dbase;
        Bp[(size_t)(d0 + dd) * CIN + c] = f2bf(tile[c][dd]);
      }
    }
  }
}

// ---------------- kernel 2: main GEMM ----------------------------------------
// Per block: Out[n0..n0+255][o][0..127] = sum_e Xb[n][IN[e]][:] . Bt[e_t][:][:]
// EXACT round-2 structure (best measured): BM=256 x BN=128, 8 waves, BK=64,
// single-buffer 48 KB LDS, 2 barriers/K-step. Residency model (r5 lesson):
// VGPR_Count 88 (incl. acc) -> 16 waves/CU reg bracket; 48 KB -> 2 blocks/CU.
// The second resident block provides cross-block load/compute overlap for
// free; every scheme that spent LDS below 2 blocks/CU regressed (r1/r5) and
// reg-staged A regressed (r3/r4). Do not touch the inner loop.
// NEW (round 6): LPT dispatch order — o = TAB.o_lpt[slot%25] puts nIter=16
// blocks first within each n-tile group, nIter=4 last -> shorter kernel tail
// (occupancy was 16.5% avg vs 50% structural ceiling = big ramp/tail share).
// XCD decode and per-nt o-grouping (L2 A-slab reuse 25x) unchanged.
__global__ __launch_bounds__(512) void so2_gemm(
    const uint16_t* __restrict__ Xb,   // [NROWS][DIM][CIN] bf16 bits
    const uint16_t* __restrict__ Bt,   // [T][COUT][CIN]    bf16 bits
    float* __restrict__ Out) {         // [NROWS][DIM][COUT]
  __shared__ __align__(16) uint16_t As[256 * 64];   // 32 KB
  __shared__ __align__(16) uint16_t Bs[128 * 64];   // 16 KB

  // XCD-aware decode: lb -> (o, n-tile), LPT-permuted o within each group
  const int lb   = blockIdx.x;            // 0..799
  const int xcd  = lb & 7;
  const int slot = lb >> 3;               // 0..99
  const int o    = TAB.o_lpt[slot % 25];  // heavy o first within an XCD group
  const int nt   = xcd + ((slot / 25) << 3);   // 0..31
  const int n0   = nt << 8;               // 256 rows per tile

  const int e0 = TAB.o_start[o];
  const int nE = TAB.o_start[o + 1] - e0;

  const int tid  = threadIdx.x;
  const int w    = tid >> 6;              // 0..7
  const int l    = tid & 63;

  // staging geometry: per issue j, rows m = j*64 + srow, LDS slot = l%8,
  // global source chunk = slot ^ (m%8)   (m%8 == l>>3 since w*8 ≡ 0 mod 8)
  const int srow = (w << 3) + (l >> 3);          // 0..63
  const int slt  = l & 7;
  const int ssrc = ((slt ^ (l >> 3)) << 3);      // element offset 0..56

  // compute geometry: wave grid 4 (rows) x 2 (cols), 64x64 per wave
  const int lr   = l & 15;
  const int quad = l >> 4;
  const int wr   = (w & 3) << 6;                 // 0,64,128,192
  const int wc   = (w >> 2) << 6;                // 0,64

  v4f acc[4][4];
  #pragma unroll
  for (int i = 0; i < 4; ++i)
    #pragma unroll
    for (int j = 0; j < 4; ++j)
      acc[i][j] = v4f{0.f, 0.f, 0.f, 0.f};

  const int nIter = nE << 1;
  for (int ki = 0; ki < nIter; ++ki) {
    const int e    = e0 + (ki >> 1);
    const int kk   = (ki & 1) << 6;            // channel half: 0 or 64
    const int irow = TAB.e_in[e];
    const int trow = TAB.e_t[e];

    const uint16_t* gA = Xb + ((size_t)(n0 + srow) * DIM + irow) * CIN + kk + ssrc;
    const uint16_t* gB = Bt + ((size_t)trow * COUT + srow) * CIN + kk + ssrc;

    if (ki) __syncthreads();                    // prev compute done reading LDS
    // A: 4 issues x 64 rows = 256 rows; B: 2 issues x 64 rows = 128 rows
    #pragma unroll
    for (int j = 0; j < 4; ++j) {
      const int m = (j << 6) + srow;
      load_lds16(gA + (size_t)(j << 6) * (DIM * CIN), &As[m * 64 + slt * 8]);
    }
    #pragma unroll
    for (int j = 0; j < 2; ++j) {
      const int m = (j << 6) + srow;
      load_lds16(gB + (size_t)(j << 6) * CIN, &Bs[m * 64 + slt * 8]);
    }
    __syncthreads();                            // staging visible

    #pragma unroll
    for (int kk2 = 0; kk2 < 2; ++kk2) {
      const int s = (((kk2 << 2) + quad) ^ (lr & 7)) << 3;
      v8bf a[4], b[4];
      #pragma unroll
      for (int i = 0; i < 4; ++i) {
        a[i] = *(const v8bf*)(&As[(wr + (i << 4) + lr) * 64 + s]);
        b[i] = *(const v8bf*)(&Bs[(wc + (i << 4) + lr) * 64 + s]);
      }
      #pragma unroll
      for (int i = 0; i < 4; ++i)
        #pragma unroll
        for (int j = 0; j < 4; ++j)
          acc[i][j] = __builtin_amdgcn_mfma_f32_16x16x32_bf16(a[i], b[j],
                                                              acc[i][j], 0, 0, 0);
    }
  }

  // epilogue: C/D layout col = lane&15 (d), row = quad*4 + r (n)
  #pragma unroll
  for (int i = 0; i < 4; ++i) {
    #pragma unroll
    for (int r = 0; r < 4; ++r) {
      const int n = n0 + wr + (i << 4) + (quad << 2) + r;
      float* op = Out + ((size_t)n * DIM + o) * COUT + wc + lr;
      #pragma unroll
      for (int j = 0; j < 4; ++j)
        op[j << 4] = acc[i][j][r];
    }
  }
}

// ---------------- launcher ---------------------------------------------------
extern "C" void kernel_launch(void* const* d_in, const int* in_sizes, int n_in,
                              void* d_out, int out_size, void* d_ws, size_t ws_size,
                              hipStream_t stream) {
  const float* X = (const float*)d_in[0];   // [8192][25][128]
  const float* W = (const float*)d_in[1];   // [85][128][128]
  float* Out = (float*)d_out;

  uint16_t* Xb = (uint16_t*)d_ws;                                   // 52.4 MB
  uint16_t* Bt = (uint16_t*)((char*)d_ws + (size_t)NROWS * DIM * CIN * 2);  // 4.75 MB

  // 1) fused prep: input fp32->bf16 cast + LDS-tiled weight transpose
  prep_kernel<<<NCVT + NWB, 256, 0, stream>>>(X, Xb, W, Bt);
  // 2) grouped GEMM, XCD-swizzled 1-D grid, 256-row tiles, LPT o-order
  so2_gemm<<<DIM * (NROWS / 256), 512, 0, stream>>>(Xb, Bt, Out);
}